// Round 11
// baseline (770.883 us; speedup 1.0000x reference)
//
#include <hip/hip_runtime.h>
#include <hip/hip_bf16.h>
#include <math.h>

// Problem constants
#define Bb 2
#define Nn 2048
#define Dd 512
#define Hh 8
#define Ll 4
#define Kk 32
#define Vv 256
#define HDh 64
#define Mrows (Bb*Nn)   // 4096

static constexpr float SCALE_QK = 0.125f;           // 1/sqrt(64)
static constexpr float INV_MOD = 1.0f / 4294967296.0f;

typedef _Float16 f16;
typedef _Float16 f16x8 __attribute__((ext_vector_type(8)));
typedef _Float16 f16x4 __attribute__((ext_vector_type(4)));
typedef _Float16 f16x2 __attribute__((ext_vector_type(2)));
typedef float f32x4 __attribute__((ext_vector_type(4)));

// ---------------- scalar precompute: c, sqrt(c), inv_tau[l] -----------------
__global__ void scal_kernel(const float* __restrict__ log_c,
                            const float* __restrict__ log_tau,
                            float* __restrict__ scal) {
    int t = threadIdx.x;
    if (t == 0) {
        float c = expf(log_c[0]);
        scal[0] = c;
        scal[1] = sqrtf(c);
    }
    if (t < Ll) scal[2 + t] = 1.0f / (expf(log_tau[t]) + 1e-8f);
}

// ------- hvec split-K GEMV, coalesced: part[b][n] = sum_{kx in slice} -------
__global__ __launch_bounds__(256)
void hvec_part_kernel(const float* __restrict__ hash_proj,
                      const float* __restrict__ Wb,
                      float* __restrict__ part) {
    const int b = blockIdx.x;            // 32 blocks, 16 k-rows each
    const int t = threadIdx.x;
    float a0 = 0.f, a1 = 0.f;
#pragma unroll
    for (int i = 0; i < 16; i++) {
        int kx = b * 16 + i;
        float hp = hash_proj[kx];
        const float* wr = Wb + (size_t)(Dd + kx) * Dd;
        a0 = fmaf(hp, wr[t], a0);
        a1 = fmaf(hp, wr[t + 256], a1);
    }
    part[b * Dd + t]       = a0;
    part[b * Dd + t + 256] = a1;
}
__global__ __launch_bounds__(256)
void hvec_red_kernel(const float* __restrict__ part, float* __restrict__ hvec) {
    const int n = blockIdx.x * 256 + threadIdx.x;   // 2 blocks
    float acc = 0.f;
#pragma unroll
    for (int b = 0; b < 32; b++) acc += part[b * Dd + n];
    hvec[n] = acc;
}

// ---------------- f32 -> f16 convert (emb) ----------------------------------
__global__ void conv_kernel(const float* __restrict__ src, f16* __restrict__ dst, int n) {
    int i = blockIdx.x * 256 + threadIdx.x;
    if (i < n) dst[i] = (f16)src[i];
}

// ---------------- bias concat for fused QKV ---------------------------------
__global__ void pack_bias_kernel(const float* __restrict__ bq, const float* __restrict__ bk,
                                 const float* __restrict__ bv, float* __restrict__ bqkv) {
    int t = blockIdx.x * 256 + threadIdx.x;   // L*1536 = 6144
    int l = t / 1536, r = t % 1536;
    const float* src = (r < 512) ? bq : ((r < 1024) ? bk : bv);
    bqkv[t] = src[l * 512 + (r & 511)];
}

// ---------------- convert + transpose: W (K x N f32) -> Wt (N x K f16) ------
__global__ __launch_bounds__(256)
void trans_kernel(const float* __restrict__ src, f16* __restrict__ dst,
                  int K, int N, long sStride, long dStride) {
    __shared__ float tile[32][33];
    const float* s = src + blockIdx.z * sStride;
    f16* d = dst + blockIdx.z * dStride;
    int k0 = blockIdx.y * 32, n0 = blockIdx.x * 32;
    int tx = threadIdx.x & 31, ty = threadIdx.x >> 5;   // ty 0..7
#pragma unroll
    for (int i = 0; i < 32; i += 8)
        tile[ty + i][tx] = s[(long)(k0 + ty + i) * N + n0 + tx];
    __syncthreads();
#pragma unroll
    for (int i = 0; i < 32; i += 8)
        d[(long)(n0 + ty + i) * K + k0 + tx] = (f16)tile[tx][ty + i];
}

// ---------------- MFMA f16 GEMM: C = op(A @ Wt^T + bias), BK=64 -------------
// Register staging + explicit LDS double-buffer: ONE barrier per K-iteration.
// Loads for tile k+1 issue before the barrier and fly during tile k's MFMA.
// LDS: 16B chunks, row = 8 chunks; chunk (m,kb) at slot m*8 + (kb^(m&7)).
template<int TN, bool GATHER, bool RANK1, bool GELU, bool RES, bool OUT16>
__global__ __launch_bounds__(256)
void mgemm(const f16* __restrict__ A, const f16* __restrict__ Wt,
           const float* __restrict__ bias,
           const int* __restrict__ gidx,
           const int* __restrict__ hashes, const float* __restrict__ hvec,
           const float* __restrict__ resid,
           void* __restrict__ Cout, int M, int N, int K) {
    constexpr int TM  = 128;
    constexpr int WN  = TN / 2;          // wave col extent (64 or 32)
    constexpr int NJT = WN / 16;         // B tiles per wave (4 or 2)
    constexpr int ACH = TM * 8;          // A chunks (16B each), BK=64 f16 = 8/row
    constexpr int BCH = TN * 8;
    constexpr int NCH = ACH + BCH;
    constexpr int NCHT = NCH / 256;      // chunks per thread (6 or 8)
    __shared__ __align__(16) f16 sm[2][NCH * 8];
    const int t = threadIdx.x;
    const int lane = t & 63;
    const int w = t >> 6;
    const int wr = w >> 1, wc = w & 1;
    const int i0 = blockIdx.y * TM, j0 = blockIdx.x * TN;

    // thread t stages slot s = t + q*256; slot s holds chunk kb = (s&7)^(m&7)
    const f16* gsrc[NCHT];
#pragma unroll
    for (int q = 0; q < NCHT; q++) {
        int c = t + q * 256;
        if (c < ACH) {
            int m = c >> 3, kb = (c & 7) ^ (m & 7);
            long row = GATHER ? (long)gidx[i0 + m] : (long)(i0 + m);
            gsrc[q] = A + row * K + kb * 8;
        } else {
            int cc = c - ACH;
            int n = cc >> 3, kb = (cc & 7) ^ (n & 7);
            gsrc[q] = Wt + (long)(j0 + n) * K + kb * 8;
        }
    }

    f32x4 acc[4][NJT];
#pragma unroll
    for (int i = 0; i < 4; i++)
#pragma unroll
        for (int j = 0; j < NJT; j++) acc[i][j] = (f32x4){0.f, 0.f, 0.f, 0.f};

    // preload tile 0
    f16x8 stg[NCHT];
#pragma unroll
    for (int q = 0; q < NCHT; q++) stg[q] = *(const f16x8*)(gsrc[q]);

    int cur = 0;
    for (int kt = 0; kt < K; kt += 64) {
        // commit tile kt to sm[cur]
#pragma unroll
        for (int q = 0; q < NCHT; q++)
            *(f16x8*)(sm[cur] + (t + q * 256) * 8) = stg[q];
        // issue loads for tile kt+64 (fly during this tile's MFMA)
        if (kt + 64 < K) {
#pragma unroll
            for (int q = 0; q < NCHT; q++) stg[q] = *(const f16x8*)(gsrc[q] + kt + 64);
        }
        __syncthreads();   // single barrier: writes(cur) visible; prior reads of other buf done

#pragma unroll
        for (int kh = 0; kh < 2; kh++) {
            f16x8 af[4], bf[NJT];
#pragma unroll
            for (int i = 0; i < 4; i++) {
                int m = wr * 64 + i * 16 + (lane & 15);
                int sl = m * 8 + ((kh * 4 + (lane >> 4)) ^ (m & 7));
                af[i] = *(const f16x8*)(sm[cur] + sl * 8);
            }
#pragma unroll
            for (int j = 0; j < NJT; j++) {
                int n = wc * WN + j * 16 + (lane & 15);
                int sl = ACH + n * 8 + ((kh * 4 + (lane >> 4)) ^ (n & 7));
                bf[j] = *(const f16x8*)(sm[cur] + sl * 8);
            }
#pragma unroll
            for (int i = 0; i < 4; i++)
#pragma unroll
                for (int j = 0; j < NJT; j++)
                    acc[i][j] = __builtin_amdgcn_mfma_f32_16x16x32_f16(af[i], bf[j], acc[i][j], 0, 0, 0);
        }
        cur ^= 1;
    }

    // epilogue: C/D layout col=lane&15, row=(lane>>4)*4+v
    float* Cf = (float*)Cout;
    f16*   Ch = (f16*)Cout;
#pragma unroll
    for (int i = 0; i < 4; i++) {
        int rbase = i0 + wr * 64 + i * 16 + ((lane >> 4) << 2);
#pragma unroll
        for (int v = 0; v < 4; v++) {
            int row = rbase + v;
            float hterm = RANK1 ? (float)hashes[row] * INV_MOD : 0.f;
#pragma unroll
            for (int j = 0; j < NJT; j++) {
                int col = j0 + wc * WN + j * 16 + (lane & 15);
                float val = acc[i][j][v] + bias[col];
                if (RANK1) val += hterm * hvec[col];
                if (GELU)  val = 0.5f * val * (1.f + erff(val * 0.7071067811865475f));
                if (RES)   val += resid[(long)row * N + col];
                if (OUT16) Ch[(long)row * N + col] = (f16)val;
                else       Cf[(long)row * N + col] = val;
            }
        }
    }
}

// ---------------- MFMA Poincare distance (BK=64, dbuf): acosh(pos@pos^T) ----
// poshl: 2048 x 1024 f16, row = [hi(512) | lo(512)], pos ~= hi+lo (22-bit).
__global__ __launch_bounds__(256)
void mdist_kernel(const f16* __restrict__ poshl, const float* __restrict__ xx,
                  const float* __restrict__ scal, float* __restrict__ dist) {
    constexpr int TM = 128, TN = 64;
    constexpr int ACH = TM * 8, BCH = TN * 8, NCH = ACH + BCH;   // 1536
    constexpr int NCHT = NCH / 256;                               // 6
    constexpr int KK = 1024;
    __shared__ __align__(16) f16 sm[2][NCH * 8];
    const int t = threadIdx.x;
    const int lane = t & 63;
    const int w = t >> 6;
    const int wr = w >> 1, wc = w & 1;
    const int i0 = blockIdx.y * TM, j0 = blockIdx.x * TN;

    const f16* gsrc[NCHT];
#pragma unroll
    for (int q = 0; q < NCHT; q++) {
        int c = t + q * 256;
        if (c < ACH) {
            int m = c >> 3, kb = (c & 7) ^ (m & 7);
            gsrc[q] = poshl + (long)(i0 + m) * KK + kb * 8;
        } else {
            int cc = c - ACH;
            int n = cc >> 3, kb = (cc & 7) ^ (n & 7);
            gsrc[q] = poshl + (long)(j0 + n) * KK + kb * 8;
        }
    }

    f32x4 acc[4][2];
#pragma unroll
    for (int i = 0; i < 4; i++)
#pragma unroll
        for (int j = 0; j < 2; j++) acc[i][j] = (f32x4){0.f, 0.f, 0.f, 0.f};

    f16x8 stg[NCHT];
#pragma unroll
    for (int q = 0; q < NCHT; q++) stg[q] = *(const f16x8*)(gsrc[q]);

    int cur = 0;
    for (int kt = 0; kt < KK; kt += 64) {
#pragma unroll
        for (int q = 0; q < NCHT; q++)
            *(f16x8*)(sm[cur] + (t + q * 256) * 8) = stg[q];
        if (kt + 64 < KK) {
#pragma unroll
            for (int q = 0; q < NCHT; q++) stg[q] = *(const f16x8*)(gsrc[q] + kt + 64);
        }
        __syncthreads();

#pragma unroll
        for (int kh = 0; kh < 2; kh++) {
            f16x8 af[4], bf[2];
#pragma unroll
            for (int i = 0; i < 4; i++) {
                int m = wr * 64 + i * 16 + (lane & 15);
                int sl = m * 8 + ((kh * 4 + (lane >> 4)) ^ (m & 7));
                af[i] = *(const f16x8*)(sm[cur] + sl * 8);
            }
#pragma unroll
            for (int j = 0; j < 2; j++) {
                int n = wc * 32 + j * 16 + (lane & 15);
                int sl = ACH + n * 8 + ((kh * 4 + (lane >> 4)) ^ (n & 7));
                bf[j] = *(const f16x8*)(sm[cur] + sl * 8);
            }
#pragma unroll
            for (int i = 0; i < 4; i++)
#pragma unroll
                for (int j = 0; j < 2; j++)
                    acc[i][j] = __builtin_amdgcn_mfma_f32_16x16x32_f16(af[i], bf[j], acc[i][j], 0, 0, 0);
        }
        cur ^= 1;
    }

    const float c = scal[0], sqc = scal[1];
#pragma unroll
    for (int i = 0; i < 4; i++) {
        int rbase = i0 + wr * 64 + i * 16 + ((lane >> 4) << 2);
#pragma unroll
        for (int v = 0; v < 4; v++) {
            int row = rbase + v;
            float xi = xx[row];
#pragma unroll
            for (int j = 0; j < 2; j++) {
                int col = j0 + wc * 32 + j * 16 + (lane & 15);
                float xj = xx[col];
                float d2 = fmaxf(xi + xj - 2.f * acc[i][j][v], 0.f);
                float denom = (1.f - c * xi) * (1.f - c * xj) + 1e-8f;
                float arg = fmaxf(1.f + 2.f * c * d2 / denom, 1.f);
                dist[(long)row * Nn + col] = acoshf(arg) / sqc;
            }
        }
    }
}

// ---------------- LayerNorm (512), single wave, float4, shuffle-only --------
__global__ __launch_bounds__(64)
void ln_kernel(const float* __restrict__ x, const float* __restrict__ g,
               const float* __restrict__ be, f16* __restrict__ xn) {
    const int row = blockIdx.x, t = threadIdx.x;
    const float4* xr = (const float4*)(x + (size_t)row * Dd);
    float4 v0 = xr[t], v1 = xr[t + 64];
    float s = v0.x + v0.y + v0.z + v0.w + v1.x + v1.y + v1.z + v1.w;
#pragma unroll
    for (int off = 32; off; off >>= 1) s += __shfl_xor(s, off, 64);
    float mean = s * (1.f / Dd);
    float d0x = v0.x - mean, d0y = v0.y - mean, d0z = v0.z - mean, d0w = v0.w - mean;
    float d1x = v1.x - mean, d1y = v1.y - mean, d1z = v1.z - mean, d1w = v1.w - mean;
    float q = d0x*d0x + d0y*d0y + d0z*d0z + d0w*d0w
            + d1x*d1x + d1y*d1y + d1z*d1z + d1w*d1w;
#pragma unroll
    for (int off = 32; off; off >>= 1) q += __shfl_xor(q, off, 64);
    float rstd = rsqrtf(q * (1.f / Dd) + 1e-5f);
    float4 g0 = ((const float4*)g)[t], g1v = ((const float4*)g)[t + 64];
    float4 b0 = ((const float4*)be)[t], b1v = ((const float4*)be)[t + 64];
    f16* xo = xn + (size_t)row * Dd;
    f16x4 o0, o1;
    o0[0] = (f16)(d0x * rstd * g0.x + b0.x);
    o0[1] = (f16)(d0y * rstd * g0.y + b0.y);
    o0[2] = (f16)(d0z * rstd * g0.z + b0.z);
    o0[3] = (f16)(d0w * rstd * g0.w + b0.w);
    o1[0] = (f16)(d1x * rstd * g1v.x + b1v.x);
    o1[1] = (f16)(d1y * rstd * g1v.y + b1v.y);
    o1[2] = (f16)(d1z * rstd * g1v.z + b1v.z);
    o1[3] = (f16)(d1w * rstd * g1v.w + b1v.w);
    *(f16x4*)(xo + t * 4)         = o0;
    *(f16x4*)(xo + (t + 64) * 4)  = o1;
}

// ---------------- expmap0 -> poshl (f16 hi|lo), xx = |pos|^2 (f32) ----------
__global__ __launch_bounds__(256)
void expmap_kernel(const float* __restrict__ vt, const float* __restrict__ scal,
                   f16* __restrict__ poshl, float* __restrict__ xx) {
    __shared__ float red[256];
    const int row = blockIdx.x, t = threadIdx.x;
    const float* vr = vt + (size_t)row * Dd;
    float v0 = vr[t], v1 = vr[t + 256];
    red[t] = v0 * v0 + v1 * v1;
    __syncthreads();
    for (int off = 128; off; off >>= 1) {
        if (t < off) red[t] += red[t + off];
        __syncthreads();
    }
    float total = red[0];
    float vn = fmaxf(sqrtf(total), 1e-8f);
    float sc = scal[1];
    float factor = tanhf(sc * vn) / (sc * vn);
    float p0 = factor * v0, p1 = factor * v1;
    f16 h0 = (f16)p0, h1 = (f16)p1;
    f16* pr = poshl + (size_t)row * 1024;
    pr[t]             = h0;
    pr[t + 256]       = h1;
    pr[512 + t]       = (f16)(p0 - (float)h0);
    pr[512 + t + 256] = (f16)(p1 - (float)h1);
    if (t == 0) xx[row] = factor * factor * total;
}

// ---------------- top-K=32: one wave per row, f32 vals in registers ---------
__global__ __launch_bounds__(64)
void topk_kernel(const float* __restrict__ dist, float* __restrict__ outd,
                 int* __restrict__ outi) {
    const int lane = threadIdx.x;
    const int n = blockIdx.x;
    const float* dr = dist + (size_t)n * Nn;
    float val[32];
#pragma unroll
    for (int i = 0; i < 32; i++) val[i] = dr[i * 64 + lane];
    float lmin = val[0];
    int   li   = 0;
#pragma unroll
    for (int i = 1; i < 32; i++) {
        if (val[i] < lmin) { lmin = val[i]; li = i; }
    }

    for (int s = 0; s < Kk; s++) {
        float wmin = lmin;
#pragma unroll
        for (int off = 32; off; off >>= 1)
            wmin = fminf(wmin, __shfl_xor(wmin, off, 64));
        const bool tiedl = (lmin == wmin);
        unsigned long long tied = __ballot(tiedl);
        const int gidx = li * 64 + lane;
        bool owner;
        if (__popcll(tied) == 1) {          // wave-uniform branch (common case)
            owner = tiedl;
        } else {                             // exact ties: lowest global index
            int cand = tiedl ? gidx : 0x7FFFFFFF;
#pragma unroll
            for (int off = 32; off; off >>= 1)
                cand = min(cand, __shfl_xor(cand, off, 64));
            owner = tiedl && (gidx == cand);
        }
        if (owner) {
            outd[n * Kk + s] = wmin;
            outi[n * Kk + s] = gidx;
#pragma unroll
            for (int i = 0; i < 32; i++)
                if (i == li) val[i] = 3.0e38f;
            lmin = val[0]; li = 0;
#pragma unroll
            for (int i = 1; i < 32; i++) {
                if (val[i] < lmin) { lmin = val[i]; li = i; }
            }
        }
    }
}

// ---------------- sparse attention: one block per (b,n), all 8 heads --------
#define KVSTR 520   // row stride in f16 (512 + 8 pad -> bank-offset rows)
__global__ __launch_bounds__(256)
void attn_kernel(const f16* __restrict__ qkv, const float* __restrict__ adist,
                 const int* __restrict__ aidx, const float* __restrict__ scal,
                 int layer, f16* __restrict__ ao) {
    __shared__ __align__(16) f16 kv[64 * KVSTR];   // [0..31]=K rows, [32..63]=V rows
    __shared__ __align__(16) f16 qs[512];
    __shared__ float ps[Hh][Kk];
    __shared__ float sdist[Kk];
    __shared__ int   sidx[Kk];
    const int t = threadIdx.x;
    const int b = blockIdx.x >> 11, n = blockIdx.x & (Nn - 1);
    const float inv_tau = scal[2 + layer];

    if (t < Kk) {
        sidx[t]  = aidx[n * Kk + t];
        sdist[t] = adist[n * Kk + t];
    }
    __syncthreads();

    {
        const size_t qrow = (size_t)(b * Nn + n) * 1536;
#pragma unroll
        for (int q = 0; q < 16; q++) {
            int c = q * 256 + t;
            int j = c >> 7, ci = c & 127;        // ci<64: K, else V
            size_t src = (size_t)(b * Nn + sidx[j]) * 1536 + 512 + ci * 8;
            int dst = (ci < 64) ? (j * KVSTR + ci * 8)
                                : ((32 + j) * KVSTR + (ci - 64) * 8);
            *(f16x8*)(kv + dst) = *(const f16x8*)(qkv + src);
        }
        if (t < 64) *(f16x8*)(qs + t * 8) = *(const f16x8*)(qkv + qrow + t * 8);
    }
    __syncthreads();

    const int h = t >> 5, j = t & 31;
    float dot = 0.f;
#pragma unroll
    for (int i = 0; i < 8; i++) {
        f16x8 qa = *(const f16x8*)(qs + h * HDh + i * 8);
        f16x8 ka = *(const f16x8*)(kv + j * KVSTR + h * HDh + i * 8);
#pragma unroll
        for (int m = 0; m < 4; m++) {
            f16x2 qp = {qa[2 * m], qa[2 * m + 1]};
            f16x2 kp = {ka[2 * m], ka[2 * m + 1]};
            dot = __builtin_amdgcn_fdot2(qp, kp, dot, false);
        }
    }
    float s = dot * SCALE_QK - sdist[j] * inv_tau;
    float mx = s;
#pragma unroll
    for (int off = 16; off; off >>= 1) mx = fmaxf(mx, __shfl_xor(mx, off, 64));
    float e = expf(s - mx);
    float sum = e;
#pragma unroll
    for (int off = 16; off; off >>= 1) sum += __shfl_xor(sum, off, 64);
    ps[h][j] = e / sum;
    __syncthreads();

    const int d2 = t & 31;
    float a0 = 0.f, a1 = 0.f;
#pragma unroll
    for (int jj = 0; jj < Kk; jj++) {
        float p = ps[h][jj];
        f16x2 vv = *(const f16x2*)(kv + (32 + jj) * KVSTR + h * HDh + d2 * 2);
        a0 = fmaf(p, (float)vv[0], a0);
        a1 = fmaf(p, (float)vv[1], a1);
    }
    f16x2 outv; outv[0] = (f16)a0; outv[1] = (f16)a1;
    *(f16x2*)(ao + (size_t)(b * Nn + n) * Dd + h * HDh + d2 * 2) = outv;
}

// ---------------- final projection: out = x[:, -1, :] @ Wout + bout ---------
__global__ void out_kernel(const float* __restrict__ x, const float* __restrict__ Wout,
                           const float* __restrict__ bout, float* __restrict__ out) {
    const int b = blockIdx.x, vc = threadIdx.x;   // 2 blocks x 256 threads
    const float* xr = x + ((size_t)(b * Nn + (Nn - 1))) * Dd;
    float acc = bout[vc];
    for (int d = 0; d < Dd; d++) acc = fmaf(xr[d], Wout[(size_t)d * Vv + vc], acc);
    out[b * Vv + vc] = acc;
}

// ---------------- workspace layout (bytes) — fully disjoint -----------------
static constexpr size_t X_OFF     = 0;          // 8388608  f32 x
static constexpr size_t XN16_OFF  = 8388608;    // 4194304  f16 xn
static constexpr size_t QKV16_OFF = 12582912;   // 12582912 f16 qkv
static constexpr size_t AO16_OFF  = 25165824;   // 4194304  f16 ao | f16 poshl (pre)
static constexpr size_t H1_OFF    = 29360128;   // 16777216 f16 h1 | f32 dist (pre)
static constexpr size_t AD_OFF    = 46137344;   // 262144
static constexpr size_t AI_OFF    = 46399488;   // 262144
static constexpr size_t SC_OFF    = 46661632;   // 256
static constexpr size_t HV_OFF    = 46661888;   // 2048
static constexpr size_t XX_OFF    = 46663936;   // 8192
static constexpr size_t BQKV_OFF  = 46672128;   // 32768
static constexpr size_t EMB16_OFF = 46704896;   // 262144
static constexpr size_t WBT_OFF   = 46967040;   // 524288
static constexpr size_t WQKVT_OFF = 47491328;   // 6291456  [L][1536][512]
static constexpr size_t WOT_OFF   = 53782784;   // 2097152  [L][512][512]
static constexpr size_t W1T_OFF   = 55879936;   // 8388608  [L][2048][512]
static constexpr size_t W2T_OFF   = 64268544;   // 8388608  [L][512][2048]
static constexpr size_t HP_OFF    = 72657152;   // 65536    hvec partials

extern "C" void kernel_launch(void* const* d_in, const int* in_sizes, int n_in,
                              void* d_out, int out_size, void* d_ws, size_t ws_size,
                              hipStream_t stream) {
    (void)in_sizes; (void)n_in; (void)out_size; (void)ws_size;
    const int*   hashes    = (const int*)  d_in[0];
    const int*   indices   = (const int*)  d_in[1];
    const float* emb       = (const float*)d_in[2];
    const float* hash_proj = (const float*)d_in[3];
    const float* Wb        = (const float*)d_in[4];
    const float* bb        = (const float*)d_in[5];
    const float* log_c     = (const float*)d_in[6];
    const float* pos_t     = (const float*)d_in[7];
    const float* Wq        = (const float*)d_in[8];
    const float* bq        = (const float*)d_in[9];
    const float* Wk        = (const float*)d_in[10];
    const float* bk        = (const float*)d_in[11];
    const float* Wv        = (const float*)d_in[12];
    const float* bv        = (const float*)d_in[13];
    const float* Wo        = (const float*)d_in[14];
    const float* bo        = (const float*)d_in[15];
    const float* W1        = (const float*)d_in[16];
    const float* b1        = (const float*)d_in[17];
    const float* W2        = (const float*)d_in[18];
    const float* b2        = (const float*)d_in[19];
    const float* g1        = (const float*)d_in[20];
    const float* be1       = (const float*)d_in[21];
    const float* g2        = (const float*)d_in[22];
    const float* be2       = (const float*)d_in[23];
    const float* log_tau   = (const float*)d_in[24];
    const float* Wout      = (const float*)d_in[25];
    const float* bout      = (const float*)d_in[26];

    char* ws = (char*)d_ws;
    float* x      = (float*)(ws + X_OFF);
    f16*   xn16   = (f16*)  (ws + XN16_OFF);
    f16*   qkv16  = (f16*)  (ws + QKV16_OFF);
    f16*   ao16   = (f16*)  (ws + AO16_OFF);
    f16*   h1     = (f16*)  (ws + H1_OFF);
    float* adist  = (float*)(ws + AD_OFF);
    int*   aidx   = (int*)  (ws + AI_OFF);
    float* scal   = (float*)(ws + SC_OFF);
    float* hvec   = (float*)(ws + HV_OFF);
    float* xxb    = (float*)(ws + XX_OFF);
    float* bqkv   = (float*)(ws + BQKV_OFF);
    f16*   emb16  = (f16*)  (ws + EMB16_OFF);
    f16*   Wbt    = (f16*)  (ws + WBT_OFF);
    f16*   Wqkvt  = (f16*)  (ws + WQKVT_OFF);
    f16*   Wot    = (f16*)  (ws + WOT_OFF);
    f16*   W1t    = (f16*)  (ws + W1T_OFF);
    f16*   W2t    = (f16*)  (ws + W2T_OFF);
    float* hpart  = (float*)(ws + HP_OFF);
    f16*   poshl  = (f16*)  (ws + AO16_OFF);   // alias, pre-loop only
    float* distb  = (float*)(ws + H1_OFF);     // alias, pre-loop only

    // --- weight prep (runs every call; graph-capture safe) ---
    scal_kernel<<<1, 64, 0, stream>>>(log_c, log_tau, scal);
    hvec_part_kernel<<<32, 256, 0, stream>>>(hash_proj, Wb, hpart);
    hvec_red_kernel<<<2, 256, 0, stream>>>(hpart, hvec);
    pack_bias_kernel<<<24, 256, 0, stream>>>(bq, bk, bv, bqkv);
    conv_kernel<<<(Vv * Dd + 255) / 256, 256, 0, stream>>>(emb, emb16, Vv * Dd);
    trans_kernel<<<dim3(16, 16, 1), 256, 0, stream>>>(Wb, Wbt, 512, 512, 0, 0);
    trans_kernel<<<dim3(16, 16, Ll), 256, 0, stream>>>(Wq, Wqkvt + 0,      512, 512, 262144, 786432);
    trans_kernel<<<dim3(16, 16, Ll), 256, 0, stream>>>(Wk, Wqkvt + 262144, 512, 512, 262144, 786432);
    trans_kernel<<<dim3(16, 16, Ll), 256, 0, stream>>>(Wv, Wqkvt + 524288, 512, 512, 262144, 786432);
    trans_kernel<<<dim3(16, 16, Ll), 256, 0, stream>>>(Wo, Wot, 512, 512, 262144, 262144);
    trans_kernel<<<dim3(64, 16, Ll), 256, 0, stream>>>(W1, W1t, 512, 2048, 1048576, 1048576);
    trans_kernel<<<dim3(16, 64, Ll), 256, 0, stream>>>(W2, W2t, 2048, 512, 1048576, 1048576);

    // --- input projection: x = emb16[indices] @ Wbt^T + hash*hvec + bb (f32 out)
    mgemm<64, true, true, false, false, false><<<dim3(8, 32), 256, 0, stream>>>(
        emb16, Wbt, bb, indices, hashes, hvec, nullptr, x, Mrows, Dd, Dd);

    // --- kNN preprocessing: expmap (hi/lo split) -> MFMA dist -> topk ---
    expmap_kernel<<<Nn, 256, 0, stream>>>(pos_t, scal, poshl, xxb);
    mdist_kernel<<<dim3(32, 16), 256, 0, stream>>>(poshl, xxb, scal, distb);
    topk_kernel<<<Nn, 64, 0, stream>>>(distb, adist, aidx);

    for (int l = 0; l < Ll; l++) {
        ln_kernel<<<Mrows, 64, 0, stream>>>(x, g1 + l * Dd, be1 + l * Dd, xn16);
        // fused QKV: M x 1536, f16 out
        mgemm<128, false, false, false, false, true><<<dim3(12, 32), 256, 0, stream>>>(
            xn16, Wqkvt + (size_t)l * 786432, bqkv + l * 1536,
            nullptr, nullptr, nullptr, nullptr, qkv16, Mrows, 1536, Dd);
        attn_kernel<<<Bb * Nn, 256, 0, stream>>>(qkv16, adist, aidx, scal, l, ao16);
        // Wo + residual, f32 out
        mgemm<64, false, false, false, true, false><<<dim3(8, 32), 256, 0, stream>>>(
            ao16, Wot + (size_t)l * 262144, bo + l * Dd,
            nullptr, nullptr, nullptr, x, x, Mrows, Dd, Dd);
        ln_kernel<<<Mrows, 64, 0, stream>>>(x, g2 + l * Dd, be2 + l * Dd, xn16);
        // W1 + GELU, f16 out
        mgemm<128, false, false, true, false, true><<<dim3(16, 32), 256, 0, stream>>>(
            xn16, W1t + (size_t)l * 1048576, b1 + l * 4 * Dd,
            nullptr, nullptr, nullptr, nullptr, h1, Mrows, 4 * Dd, Dd);
        // W2 + residual, f32 out
        mgemm<64, false, false, false, true, false><<<dim3(8, 32), 256, 0, stream>>>(
            h1, W2t + (size_t)l * 1048576, b2 + l * Dd,
            nullptr, nullptr, nullptr, x, x, Mrows, Dd, 4 * Dd);
    }

    out_kernel<<<Bb, Vv, 0, stream>>>(x, Wout, bout, (float*)d_out);
}

// Round 12
// 727.272 us; speedup vs baseline: 1.0600x; 1.0600x over previous
//
#include <hip/hip_runtime.h>
#include <hip/hip_bf16.h>
#include <math.h>

// Problem constants
#define Bb 2
#define Nn 2048
#define Dd 512
#define Hh 8
#define Ll 4
#define Kk 32
#define Vv 256
#define HDh 64
#define Mrows (Bb*Nn)   // 4096

static constexpr float SCALE_QK = 0.125f;           // 1/sqrt(64)
static constexpr float INV_MOD = 1.0f / 4294967296.0f;

typedef _Float16 f16;
typedef _Float16 f16x8 __attribute__((ext_vector_type(8)));
typedef _Float16 f16x4 __attribute__((ext_vector_type(4)));
typedef _Float16 f16x2 __attribute__((ext_vector_type(2)));
typedef float f32x4 __attribute__((ext_vector_type(4)));

// ---------------- scalar precompute: c, sqrt(c), inv_tau[l] -----------------
__global__ void scal_kernel(const float* __restrict__ log_c,
                            const float* __restrict__ log_tau,
                            float* __restrict__ scal) {
    int t = threadIdx.x;
    if (t == 0) {
        float c = expf(log_c[0]);
        scal[0] = c;
        scal[1] = sqrtf(c);
    }
    if (t < Ll) scal[2 + t] = 1.0f / (expf(log_tau[t]) + 1e-8f);
}

// ------- hvec split-K GEMV, coalesced: part[b][n] = sum_{kx in slice} -------
__global__ __launch_bounds__(256)
void hvec_part_kernel(const float* __restrict__ hash_proj,
                      const float* __restrict__ Wb,
                      float* __restrict__ part) {
    const int b = blockIdx.x;            // 32 blocks, 16 k-rows each
    const int t = threadIdx.x;
    float a0 = 0.f, a1 = 0.f;
#pragma unroll
    for (int i = 0; i < 16; i++) {
        int kx = b * 16 + i;
        float hp = hash_proj[kx];
        const float* wr = Wb + (size_t)(Dd + kx) * Dd;
        a0 = fmaf(hp, wr[t], a0);
        a1 = fmaf(hp, wr[t + 256], a1);
    }
    part[b * Dd + t]       = a0;
    part[b * Dd + t + 256] = a1;
}
__global__ __launch_bounds__(256)
void hvec_red_kernel(const float* __restrict__ part, float* __restrict__ hvec) {
    const int n = blockIdx.x * 256 + threadIdx.x;   // 2 blocks
    float acc = 0.f;
#pragma unroll
    for (int b = 0; b < 32; b++) acc += part[b * Dd + n];
    hvec[n] = acc;
}

// ---------------- f32 -> f16 convert (emb) ----------------------------------
__global__ void conv_kernel(const float* __restrict__ src, f16* __restrict__ dst, int n) {
    int i = blockIdx.x * 256 + threadIdx.x;
    if (i < n) dst[i] = (f16)src[i];
}

// ---------------- bias concat for fused QKV ---------------------------------
__global__ void pack_bias_kernel(const float* __restrict__ bq, const float* __restrict__ bk,
                                 const float* __restrict__ bv, float* __restrict__ bqkv) {
    int t = blockIdx.x * 256 + threadIdx.x;   // L*1536 = 6144
    int l = t / 1536, r = t % 1536;
    const float* src = (r < 512) ? bq : ((r < 1024) ? bk : bv);
    bqkv[t] = src[l * 512 + (r & 511)];
}

// ---------------- convert + transpose: W (K x N f32) -> Wt (N x K f16) ------
__global__ __launch_bounds__(256)
void trans_kernel(const float* __restrict__ src, f16* __restrict__ dst,
                  int K, int N, long sStride, long dStride) {
    __shared__ float tile[32][33];
    const float* s = src + blockIdx.z * sStride;
    f16* d = dst + blockIdx.z * dStride;
    int k0 = blockIdx.y * 32, n0 = blockIdx.x * 32;
    int tx = threadIdx.x & 31, ty = threadIdx.x >> 5;   // ty 0..7
#pragma unroll
    for (int i = 0; i < 32; i += 8)
        tile[ty + i][tx] = s[(long)(k0 + ty + i) * N + n0 + tx];
    __syncthreads();
#pragma unroll
    for (int i = 0; i < 32; i += 8)
        d[(long)(n0 + ty + i) * K + k0 + tx] = (f16)tile[tx][ty + i];
}

// ---- merged transpose for the four 512x512 weight families (z = w*4 + l) ---
__global__ __launch_bounds__(256)
void trans4_kernel(const float* __restrict__ Wq, const float* __restrict__ Wk,
                   const float* __restrict__ Wv, const float* __restrict__ Wo,
                   f16* __restrict__ Wqkvt, f16* __restrict__ Wot) {
    __shared__ float tile[32][33];
    const int which = blockIdx.z >> 2, l = blockIdx.z & 3;
    const float* s;
    f16* d;
    switch (which) {
        case 0: s = Wq + (size_t)l * 262144; d = Wqkvt + (size_t)l * 786432;          break;
        case 1: s = Wk + (size_t)l * 262144; d = Wqkvt + (size_t)l * 786432 + 262144; break;
        case 2: s = Wv + (size_t)l * 262144; d = Wqkvt + (size_t)l * 786432 + 524288; break;
        default:s = Wo + (size_t)l * 262144; d = Wot   + (size_t)l * 262144;          break;
    }
    int k0 = blockIdx.y * 32, n0 = blockIdx.x * 32;
    int tx = threadIdx.x & 31, ty = threadIdx.x >> 5;
#pragma unroll
    for (int i = 0; i < 32; i += 8)
        tile[ty + i][tx] = s[(long)(k0 + ty + i) * 512 + n0 + tx];
    __syncthreads();
#pragma unroll
    for (int i = 0; i < 32; i += 8)
        d[(long)(n0 + ty + i) * 512 + k0 + tx] = (f16)tile[tx][ty + i];
}

// ---------------- MFMA f16 GEMM: C = op(A @ Wt^T + bias), BK=64 -------------
// Register staging, 2 barriers/iter (compiler pipelines next-iter register
// loads across the MFMA; explicit dbuf/single-barrier REGRESSED: R11 post-mortem
// — the barrier drains vmcnt(0), serializing prefetch issued before it).
// LDS: 16B chunks, row = 8 chunks; chunk (m,kb) at slot m*8 + (kb^(m&7)).
template<int TN, bool GATHER, bool RANK1, bool GELU, bool RES, bool OUT16>
__global__ __launch_bounds__(256)
void mgemm(const f16* __restrict__ A, const f16* __restrict__ Wt,
           const float* __restrict__ bias,
           const int* __restrict__ gidx,
           const int* __restrict__ hashes, const float* __restrict__ hvec,
           const float* __restrict__ resid,
           void* __restrict__ Cout, int M, int N, int K) {
    constexpr int TM  = 128;
    constexpr int WN  = TN / 2;          // wave col extent (64 or 32)
    constexpr int NJT = WN / 16;         // B tiles per wave (4 or 2)
    constexpr int ACH = TM * 8;          // A chunks (16B each), BK=64 f16 = 8/row
    constexpr int BCH = TN * 8;
    constexpr int NCH = ACH + BCH;
    constexpr int NCHT = NCH / 256;      // chunks per thread (6 or 8)
    __shared__ __align__(16) f16 sm[NCH * 8];
    const int t = threadIdx.x;
    const int lane = t & 63;
    const int w = t >> 6;
    const int wr = w >> 1, wc = w & 1;
    const int i0 = blockIdx.y * TM, j0 = blockIdx.x * TN;

    // thread t stages slot s = t + q*256; slot s holds chunk kb = (s&7)^(m&7)
    const f16* gsrc[NCHT];
#pragma unroll
    for (int q = 0; q < NCHT; q++) {
        int c = t + q * 256;
        if (c < ACH) {
            int m = c >> 3, kb = (c & 7) ^ (m & 7);
            long row = GATHER ? (long)gidx[i0 + m] : (long)(i0 + m);
            gsrc[q] = A + row * K + kb * 8;
        } else {
            int cc = c - ACH;
            int n = cc >> 3, kb = (cc & 7) ^ (n & 7);
            gsrc[q] = Wt + (long)(j0 + n) * K + kb * 8;
        }
    }

    f32x4 acc[4][NJT];
#pragma unroll
    for (int i = 0; i < 4; i++)
#pragma unroll
        for (int j = 0; j < NJT; j++) acc[i][j] = (f32x4){0.f, 0.f, 0.f, 0.f};

    for (int kt = 0; kt < K; kt += 64) {
        f16x8 stg[NCHT];
#pragma unroll
        for (int q = 0; q < NCHT; q++) stg[q] = *(const f16x8*)(gsrc[q] + kt);
        __syncthreads();   // previous iteration's LDS reads complete
#pragma unroll
        for (int q = 0; q < NCHT; q++)
            *(f16x8*)(sm + (t + q * 256) * 8) = stg[q];
        __syncthreads();

#pragma unroll
        for (int kh = 0; kh < 2; kh++) {
            f16x8 af[4], bf[NJT];
#pragma unroll
            for (int i = 0; i < 4; i++) {
                int m = wr * 64 + i * 16 + (lane & 15);
                int sl = m * 8 + ((kh * 4 + (lane >> 4)) ^ (m & 7));
                af[i] = *(const f16x8*)(sm + sl * 8);
            }
#pragma unroll
            for (int j = 0; j < NJT; j++) {
                int n = wc * WN + j * 16 + (lane & 15);
                int sl = ACH + n * 8 + ((kh * 4 + (lane >> 4)) ^ (n & 7));
                bf[j] = *(const f16x8*)(sm + sl * 8);
            }
#pragma unroll
            for (int i = 0; i < 4; i++)
#pragma unroll
                for (int j = 0; j < NJT; j++)
                    acc[i][j] = __builtin_amdgcn_mfma_f32_16x16x32_f16(af[i], bf[j], acc[i][j], 0, 0, 0);
        }
    }

    // epilogue: C/D layout col=lane&15, row=(lane>>4)*4+v
    float* Cf = (float*)Cout;
    f16*   Ch = (f16*)Cout;
#pragma unroll
    for (int i = 0; i < 4; i++) {
        int rbase = i0 + wr * 64 + i * 16 + ((lane >> 4) << 2);
#pragma unroll
        for (int v = 0; v < 4; v++) {
            int row = rbase + v;
            float hterm = RANK1 ? (float)hashes[row] * INV_MOD : 0.f;
#pragma unroll
            for (int j = 0; j < NJT; j++) {
                int col = j0 + wc * WN + j * 16 + (lane & 15);
                float val = acc[i][j][v] + bias[col];
                if (RANK1) val += hterm * hvec[col];
                if (GELU)  val = 0.5f * val * (1.f + erff(val * 0.7071067811865475f));
                if (RES)   val += resid[(long)row * N + col];
                if (OUT16) Ch[(long)row * N + col] = (f16)val;
                else       Cf[(long)row * N + col] = val;
            }
        }
    }
}

// ---------------- MFMA Poincare distance (BK=64): acosh of pos@pos^T --------
// poshl: 2048 x 1024 f16, row = [hi(512) | lo(512)], pos ~= hi+lo (22-bit).
__global__ __launch_bounds__(256)
void mdist_kernel(const f16* __restrict__ poshl, const float* __restrict__ xx,
                  const float* __restrict__ scal, float* __restrict__ dist) {
    constexpr int TM = 128, TN = 64;
    constexpr int ACH = TM * 8, BCH = TN * 8, NCH = ACH + BCH;   // 1536
    constexpr int NCHT = NCH / 256;                               // 6
    constexpr int KK = 1024;
    __shared__ __align__(16) f16 sm[NCH * 8];
    const int t = threadIdx.x;
    const int lane = t & 63;
    const int w = t >> 6;
    const int wr = w >> 1, wc = w & 1;
    const int i0 = blockIdx.y * TM, j0 = blockIdx.x * TN;

    const f16* gsrc[NCHT];
#pragma unroll
    for (int q = 0; q < NCHT; q++) {
        int c = t + q * 256;
        if (c < ACH) {
            int m = c >> 3, kb = (c & 7) ^ (m & 7);
            gsrc[q] = poshl + (long)(i0 + m) * KK + kb * 8;
        } else {
            int cc = c - ACH;
            int n = cc >> 3, kb = (cc & 7) ^ (n & 7);
            gsrc[q] = poshl + (long)(j0 + n) * KK + kb * 8;
        }
    }

    f32x4 acc[4][2];
#pragma unroll
    for (int i = 0; i < 4; i++)
#pragma unroll
        for (int j = 0; j < 2; j++) acc[i][j] = (f32x4){0.f, 0.f, 0.f, 0.f};

    for (int kt = 0; kt < KK; kt += 64) {
        f16x8 stg[NCHT];
#pragma unroll
        for (int q = 0; q < NCHT; q++) stg[q] = *(const f16x8*)(gsrc[q] + kt);
        __syncthreads();
#pragma unroll
        for (int q = 0; q < NCHT; q++)
            *(f16x8*)(sm + (t + q * 256) * 8) = stg[q];
        __syncthreads();

#pragma unroll
        for (int kh = 0; kh < 2; kh++) {
            f16x8 af[4], bf[2];
#pragma unroll
            for (int i = 0; i < 4; i++) {
                int m = wr * 64 + i * 16 + (lane & 15);
                int sl = m * 8 + ((kh * 4 + (lane >> 4)) ^ (m & 7));
                af[i] = *(const f16x8*)(sm + sl * 8);
            }
#pragma unroll
            for (int j = 0; j < 2; j++) {
                int n = wc * 32 + j * 16 + (lane & 15);
                int sl = ACH + n * 8 + ((kh * 4 + (lane >> 4)) ^ (n & 7));
                bf[j] = *(const f16x8*)(sm + sl * 8);
            }
#pragma unroll
            for (int i = 0; i < 4; i++)
#pragma unroll
                for (int j = 0; j < 2; j++)
                    acc[i][j] = __builtin_amdgcn_mfma_f32_16x16x32_f16(af[i], bf[j], acc[i][j], 0, 0, 0);
        }
    }

    const float c = scal[0], sqc = scal[1];
#pragma unroll
    for (int i = 0; i < 4; i++) {
        int rbase = i0 + wr * 64 + i * 16 + ((lane >> 4) << 2);
#pragma unroll
        for (int v = 0; v < 4; v++) {
            int row = rbase + v;
            float xi = xx[row];
#pragma unroll
            for (int j = 0; j < 2; j++) {
                int col = j0 + wc * 32 + j * 16 + (lane & 15);
                float xj = xx[col];
                float d2 = fmaxf(xi + xj - 2.f * acc[i][j][v], 0.f);
                float denom = (1.f - c * xi) * (1.f - c * xj) + 1e-8f;
                float arg = fmaxf(1.f + 2.f * c * d2 / denom, 1.f);
                dist[(long)row * Nn + col] = acoshf(arg) / sqc;
            }
        }
    }
}

// ---------------- LayerNorm (512), single wave, float4, shuffle-only --------
__global__ __launch_bounds__(64)
void ln_kernel(const float* __restrict__ x, const float* __restrict__ g,
               const float* __restrict__ be, f16* __restrict__ xn) {
    const int row = blockIdx.x, t = threadIdx.x;
    const float4* xr = (const float4*)(x + (size_t)row * Dd);
    float4 v0 = xr[t], v1 = xr[t + 64];
    float s = v0.x + v0.y + v0.z + v0.w + v1.x + v1.y + v1.z + v1.w;
#pragma unroll
    for (int off = 32; off; off >>= 1) s += __shfl_xor(s, off, 64);
    float mean = s * (1.f / Dd);
    float d0x = v0.x - mean, d0y = v0.y - mean, d0z = v0.z - mean, d0w = v0.w - mean;
    float d1x = v1.x - mean, d1y = v1.y - mean, d1z = v1.z - mean, d1w = v1.w - mean;
    float q = d0x*d0x + d0y*d0y + d0z*d0z + d0w*d0w
            + d1x*d1x + d1y*d1y + d1z*d1z + d1w*d1w;
#pragma unroll
    for (int off = 32; off; off >>= 1) q += __shfl_xor(q, off, 64);
    float rstd = rsqrtf(q * (1.f / Dd) + 1e-5f);
    float4 g0 = ((const float4*)g)[t], g1v = ((const float4*)g)[t + 64];
    float4 b0 = ((const float4*)be)[t], b1v = ((const float4*)be)[t + 64];
    f16* xo = xn + (size_t)row * Dd;
    f16x4 o0, o1;
    o0[0] = (f16)(d0x * rstd * g0.x + b0.x);
    o0[1] = (f16)(d0y * rstd * g0.y + b0.y);
    o0[2] = (f16)(d0z * rstd * g0.z + b0.z);
    o0[3] = (f16)(d0w * rstd * g0.w + b0.w);
    o1[0] = (f16)(d1x * rstd * g1v.x + b1v.x);
    o1[1] = (f16)(d1y * rstd * g1v.y + b1v.y);
    o1[2] = (f16)(d1z * rstd * g1v.z + b1v.z);
    o1[3] = (f16)(d1w * rstd * g1v.w + b1v.w);
    *(f16x4*)(xo + t * 4)         = o0;
    *(f16x4*)(xo + (t + 64) * 4)  = o1;
}

// ---------------- expmap0 -> poshl (f16 hi|lo), xx = |pos|^2 (f32) ----------
__global__ __launch_bounds__(256)
void expmap_kernel(const float* __restrict__ vt, const float* __restrict__ scal,
                   f16* __restrict__ poshl, float* __restrict__ xx) {
    __shared__ float red[256];
    const int row = blockIdx.x, t = threadIdx.x;
    const float* vr = vt + (size_t)row * Dd;
    float v0 = vr[t], v1 = vr[t + 256];
    red[t] = v0 * v0 + v1 * v1;
    __syncthreads();
    for (int off = 128; off; off >>= 1) {
        if (t < off) red[t] += red[t + off];
        __syncthreads();
    }
    float total = red[0];
    float vn = fmaxf(sqrtf(total), 1e-8f);
    float sc = scal[1];
    float factor = tanhf(sc * vn) / (sc * vn);
    float p0 = factor * v0, p1 = factor * v1;
    f16 h0 = (f16)p0, h1 = (f16)p1;
    f16* pr = poshl + (size_t)row * 1024;
    pr[t]             = h0;
    pr[t + 256]       = h1;
    pr[512 + t]       = (f16)(p0 - (float)h0);
    pr[512 + t + 256] = (f16)(p1 - (float)h1);
    if (t == 0) xx[row] = factor * factor * total;
}

// ---------------- top-K=32: one wave per row, f32 vals in registers ---------
__global__ __launch_bounds__(64)
void topk_kernel(const float* __restrict__ dist, float* __restrict__ outd,
                 int* __restrict__ outi) {
    const int lane = threadIdx.x;
    const int n = blockIdx.x;
    const float* dr = dist + (size_t)n * Nn;
    float val[32];
#pragma unroll
    for (int i = 0; i < 32; i++) val[i] = dr[i * 64 + lane];
    float lmin = val[0];
    int   li   = 0;
#pragma unroll
    for (int i = 1; i < 32; i++) {
        if (val[i] < lmin) { lmin = val[i]; li = i; }
    }

    for (int s = 0; s < Kk; s++) {
        float wmin = lmin;
#pragma unroll
        for (int off = 32; off; off >>= 1)
            wmin = fminf(wmin, __shfl_xor(wmin, off, 64));
        const bool tiedl = (lmin == wmin);
        unsigned long long tied = __ballot(tiedl);
        const int gidx = li * 64 + lane;
        bool owner;
        if (__popcll(tied) == 1) {          // wave-uniform branch (common case)
            owner = tiedl;
        } else {                             // exact ties: lowest global index
            int cand = tiedl ? gidx : 0x7FFFFFFF;
#pragma unroll
            for (int off = 32; off; off >>= 1)
                cand = min(cand, __shfl_xor(cand, off, 64));
            owner = tiedl && (gidx == cand);
        }
        if (owner) {
            outd[n * Kk + s] = wmin;
            outi[n * Kk + s] = gidx;
#pragma unroll
            for (int i = 0; i < 32; i++)
                if (i == li) val[i] = 3.0e38f;
            lmin = val[0]; li = 0;
#pragma unroll
            for (int i = 1; i < 32; i++) {
                if (val[i] < lmin) { lmin = val[i]; li = i; }
            }
        }
    }
}

// ---------------- sparse attention: one block per (b,n), all 8 heads --------
#define KVSTR 520   // row stride in f16 (512 + 8 pad -> bank-offset rows)
__global__ __launch_bounds__(256)
void attn_kernel(const f16* __restrict__ qkv, const float* __restrict__ adist,
                 const int* __restrict__ aidx, const float* __restrict__ scal,
                 int layer, f16* __restrict__ ao) {
    __shared__ __align__(16) f16 kv[64 * KVSTR];   // [0..31]=K rows, [32..63]=V rows
    __shared__ __align__(16) f16 qs[512];
    __shared__ float ps[Hh][Kk];
    __shared__ float sdist[Kk];
    __shared__ int   sidx[Kk];
    const int t = threadIdx.x;
    const int b = blockIdx.x >> 11, n = blockIdx.x & (Nn - 1);
    const float inv_tau = scal[2 + layer];

    if (t < Kk) {
        sidx[t]  = aidx[n * Kk + t];
        sdist[t] = adist[n * Kk + t];
    }
    __syncthreads();

    {
        const size_t qrow = (size_t)(b * Nn + n) * 1536;
#pragma unroll
        for (int q = 0; q < 16; q++) {
            int c = q * 256 + t;
            int j = c >> 7, ci = c & 127;        // ci<64: K, else V
            size_t src = (size_t)(b * Nn + sidx[j]) * 1536 + 512 + ci * 8;
            int dst = (ci < 64) ? (j * KVSTR + ci * 8)
                                : ((32 + j) * KVSTR + (ci - 64) * 8);
            *(f16x8*)(kv + dst) = *(const f16x8*)(qkv + src);
        }
        if (t < 64) *(f16x8*)(qs + t * 8) = *(const f16x8*)(qkv + qrow + t * 8);
    }
    __syncthreads();

    const int h = t >> 5, j = t & 31;
    float dot = 0.f;
#pragma unroll
    for (int i = 0; i < 8; i++) {
        f16x8 qa = *(const f16x8*)(qs + h * HDh + i * 8);
        f16x8 ka = *(const f16x8*)(kv + j * KVSTR + h * HDh + i * 8);
#pragma unroll
        for (int m = 0; m < 4; m++) {
            f16x2 qp = {qa[2 * m], qa[2 * m + 1]};
            f16x2 kp = {ka[2 * m], ka[2 * m + 1]};
            dot = __builtin_amdgcn_fdot2(qp, kp, dot, false);
        }
    }
    float s = dot * SCALE_QK - sdist[j] * inv_tau;
    float mx = s;
#pragma unroll
    for (int off = 16; off; off >>= 1) mx = fmaxf(mx, __shfl_xor(mx, off, 64));
    float e = expf(s - mx);
    float sum = e;
#pragma unroll
    for (int off = 16; off; off >>= 1) sum += __shfl_xor(sum, off, 64);
    ps[h][j] = e / sum;
    __syncthreads();

    const int d2 = t & 31;
    float a0 = 0.f, a1 = 0.f;
#pragma unroll
    for (int jj = 0; jj < Kk; jj++) {
        float p = ps[h][jj];
        f16x2 vv = *(const f16x2*)(kv + (32 + jj) * KVSTR + h * HDh + d2 * 2);
        a0 = fmaf(p, (float)vv[0], a0);
        a1 = fmaf(p, (float)vv[1], a1);
    }
    f16x2 outv; outv[0] = (f16)a0; outv[1] = (f16)a1;
    *(f16x2*)(ao + (size_t)(b * Nn + n) * Dd + h * HDh + d2 * 2) = outv;
}

// ---------------- final projection: out = x[:, -1, :] @ Wout + bout ---------
__global__ void out_kernel(const float* __restrict__ x, const float* __restrict__ Wout,
                           const float* __restrict__ bout, float* __restrict__ out) {
    const int b = blockIdx.x, vc = threadIdx.x;   // 2 blocks x 256 threads
    const float* xr = x + ((size_t)(b * Nn + (Nn - 1))) * Dd;
    float acc = bout[vc];
    for (int d = 0; d < Dd; d++) acc = fmaf(xr[d], Wout[(size_t)d * Vv + vc], acc);
    out[b * Vv + vc] = acc;
}

// ---------------- workspace layout (bytes) — fully disjoint -----------------
static constexpr size_t X_OFF     = 0;          // 8388608  f32 x
static constexpr size_t XN16_OFF  = 8388608;    // 4194304  f16 xn
static constexpr size_t QKV16_OFF = 12582912;   // 12582912 f16 qkv
static constexpr size_t AO16_OFF  = 25165824;   // 4194304  f16 ao | f16 poshl (pre)
static constexpr size_t H1_OFF    = 29360128;   // 16777216 f16 h1 | f32 dist (pre)
static constexpr size_t AD_OFF    = 46137344;   // 262144
static constexpr size_t AI_OFF    = 46399488;   // 262144
static constexpr size_t SC_OFF    = 46661632;   // 256
static constexpr size_t HV_OFF    = 46661888;   // 2048
static constexpr size_t XX_OFF    = 46663936;   // 8192
static constexpr size_t BQKV_OFF  = 46672128;   // 32768
static constexpr size_t EMB16_OFF = 46704896;   // 262144
static constexpr size_t WBT_OFF   = 46967040;   // 524288
static constexpr size_t WQKVT_OFF = 47491328;   // 6291456  [L][1536][512]
static constexpr size_t WOT_OFF   = 53782784;   // 2097152  [L][512][512]
static constexpr size_t W1T_OFF   = 55879936;   // 8388608  [L][2048][512]
static constexpr size_t W2T_OFF   = 64268544;   // 8388608  [L][512][2048]
static constexpr size_t HP_OFF    = 72657152;   // 65536    hvec partials

extern "C" void kernel_launch(void* const* d_in, const int* in_sizes, int n_in,
                              void* d_out, int out_size, void* d_ws, size_t ws_size,
                              hipStream_t stream) {
    (void)in_sizes; (void)n_in; (void)out_size; (void)ws_size;
    const int*   hashes    = (const int*)  d_in[0];
    const int*   indices   = (const int*)  d_in[1];
    const float* emb       = (const float*)d_in[2];
    const float* hash_proj = (const float*)d_in[3];
    const float* Wb        = (const float*)d_in[4];
    const float* bb        = (const float*)d_in[5];
    const float* log_c     = (const float*)d_in[6];
    const float* pos_t     = (const float*)d_in[7];
    const float* Wq        = (const float*)d_in[8];
    const float* bq        = (const float*)d_in[9];
    const float* Wk        = (const float*)d_in[10];
    const float* bk        = (const float*)d_in[11];
    const float* Wv        = (const float*)d_in[12];
    const float* bv        = (const float*)d_in[13];
    const float* Wo        = (const float*)d_in[14];
    const float* bo        = (const float*)d_in[15];
    const float* W1        = (const float*)d_in[16];
    const float* b1        = (const float*)d_in[17];
    const float* W2        = (const float*)d_in[18];
    const float* b2        = (const float*)d_in[19];
    const float* g1        = (const float*)d_in[20];
    const float* be1       = (const float*)d_in[21];
    const float* g2        = (const float*)d_in[22];
    const float* be2       = (const float*)d_in[23];
    const float* log_tau   = (const float*)d_in[24];
    const float* Wout      = (const float*)d_in[25];
    const float* bout      = (const float*)d_in[26];

    char* ws = (char*)d_ws;
    float* x      = (float*)(ws + X_OFF);
    f16*   xn16   = (f16*)  (ws + XN16_OFF);
    f16*   qkv16  = (f16*)  (ws + QKV16_OFF);
    f16*   ao16   = (f16*)  (ws + AO16_OFF);
    f16*   h1     = (f16*)  (ws + H1_OFF);
    float* adist  = (float*)(ws + AD_OFF);
    int*   aidx   = (int*)  (ws + AI_OFF);
    float* scal   = (float*)(ws + SC_OFF);
    float* hvec   = (float*)(ws + HV_OFF);
    float* xxb    = (float*)(ws + XX_OFF);
    float* bqkv   = (float*)(ws + BQKV_OFF);
    f16*   emb16  = (f16*)  (ws + EMB16_OFF);
    f16*   Wbt    = (f16*)  (ws + WBT_OFF);
    f16*   Wqkvt  = (f16*)  (ws + WQKVT_OFF);
    f16*   Wot    = (f16*)  (ws + WOT_OFF);
    f16*   W1t    = (f16*)  (ws + W1T_OFF);
    f16*   W2t    = (f16*)  (ws + W2T_OFF);
    float* hpart  = (float*)(ws + HP_OFF);
    f16*   poshl  = (f16*)  (ws + AO16_OFF);   // alias, pre-loop only
    float* distb  = (float*)(ws + H1_OFF);     // alias, pre-loop only

    // --- weight prep (runs every call; graph-capture safe) ---
    scal_kernel<<<1, 64, 0, stream>>>(log_c, log_tau, scal);
    hvec_part_kernel<<<32, 256, 0, stream>>>(hash_proj, Wb, hpart);
    hvec_red_kernel<<<2, 256, 0, stream>>>(hpart, hvec);
    pack_bias_kernel<<<24, 256, 0, stream>>>(bq, bk, bv, bqkv);
    conv_kernel<<<(Vv * Dd + 255) / 256, 256, 0, stream>>>(emb, emb16, Vv * Dd);
    trans_kernel<<<dim3(16, 16, 1), 256, 0, stream>>>(Wb, Wbt, 512, 512, 0, 0);
    trans4_kernel<<<dim3(16, 16, 16), 256, 0, stream>>>(Wq, Wk, Wv, Wo, Wqkvt, Wot);
    trans_kernel<<<dim3(64, 16, Ll), 256, 0, stream>>>(W1, W1t, 512, 2048, 1048576, 1048576);
    trans_kernel<<<dim3(16, 64, Ll), 256, 0, stream>>>(W2, W2t, 2048, 512, 1048576, 1048576);

    // --- input projection: x = emb16[indices] @ Wbt^T + hash*hvec + bb (f32 out)
    mgemm<64, true, true, false, false, false><<<dim3(8, 32), 256, 0, stream>>>(
        emb16, Wbt, bb, indices, hashes, hvec, nullptr, x, Mrows, Dd, Dd);

    // --- kNN preprocessing: expmap (hi/lo split) -> MFMA dist -> topk ---
    expmap_kernel<<<Nn, 256, 0, stream>>>(pos_t, scal, poshl, xxb);
    mdist_kernel<<<dim3(32, 16), 256, 0, stream>>>(poshl, xxb, scal, distb);
    topk_kernel<<<Nn, 64, 0, stream>>>(distb, adist, aidx);

    for (int l = 0; l < Ll; l++) {
        ln_kernel<<<Mrows, 64, 0, stream>>>(x, g1 + l * Dd, be1 + l * Dd, xn16);
        // fused QKV: M x 1536, f16 out
        mgemm<128, false, false, false, false, true><<<dim3(12, 32), 256, 0, stream>>>(
            xn16, Wqkvt + (size_t)l * 786432, bqkv + l * 1536,
            nullptr, nullptr, nullptr, nullptr, qkv16, Mrows, 1536, Dd);
        attn_kernel<<<Bb * Nn, 256, 0, stream>>>(qkv16, adist, aidx, scal, l, ao16);
        // Wo + residual, f32 out
        mgemm<64, false, false, false, true, false><<<dim3(8, 32), 256, 0, stream>>>(
            ao16, Wot + (size_t)l * 262144, bo + l * Dd,
            nullptr, nullptr, nullptr, x, x, Mrows, Dd, Dd);
        ln_kernel<<<Mrows, 64, 0, stream>>>(x, g2 + l * Dd, be2 + l * Dd, xn16);
        // W1 + GELU, f16 out
        mgemm<128, false, false, true, false, true><<<dim3(16, 32), 256, 0, stream>>>(
            xn16, W1t + (size_t)l * 1048576, b1 + l * 4 * Dd,
            nullptr, nullptr, nullptr, nullptr, h1, Mrows, 4 * Dd, Dd);
        // W2 + residual, f32 out
        mgemm<64, false, false, false, true, false><<<dim3(8, 32), 256, 0, stream>>>(
            h1, W2t + (size_t)l * 1048576, b2 + l * Dd,
            nullptr, nullptr, nullptr, x, x, Mrows, Dd, 4 * Dd);
    }

    out_kernel<<<Bb, Vv, 0, stream>>>(x, Wout, bout, (float*)d_out);
}

// Round 13
// 679.820 us; speedup vs baseline: 1.1340x; 1.0698x over previous
//
#include <hip/hip_runtime.h>
#include <hip/hip_bf16.h>
#include <math.h>

// Problem constants
#define Bb 2
#define Nn 2048
#define Dd 512
#define Hh 8
#define Ll 4
#define Kk 32
#define Vv 256
#define HDh 64
#define Mrows (Bb*Nn)   // 4096

static constexpr float SCALE_QK = 0.125f;           // 1/sqrt(64)
static constexpr float INV_MOD = 1.0f / 4294967296.0f;

typedef _Float16 f16;
typedef _Float16 f16x8 __attribute__((ext_vector_type(8)));
typedef _Float16 f16x4 __attribute__((ext_vector_type(4)));
typedef _Float16 f16x2 __attribute__((ext_vector_type(2)));
typedef float f32x4 __attribute__((ext_vector_type(4)));

// ---------------- scalar precompute: c, sqrt(c), inv_tau[l] -----------------
__global__ void scal_kernel(const float* __restrict__ log_c,
                            const float* __restrict__ log_tau,
                            float* __restrict__ scal) {
    int t = threadIdx.x;
    if (t == 0) {
        float c = expf(log_c[0]);
        scal[0] = c;
        scal[1] = sqrtf(c);
    }
    if (t < Ll) scal[2 + t] = 1.0f / (expf(log_tau[t]) + 1e-8f);
}

// ------- hvec split-K GEMV, coalesced: part[b][n] = sum_{kx in slice} -------
__global__ __launch_bounds__(256)
void hvec_part_kernel(const float* __restrict__ hash_proj,
                      const float* __restrict__ Wb,
                      float* __restrict__ part) {
    const int b = blockIdx.x;            // 32 blocks, 16 k-rows each
    const int t = threadIdx.x;
    float a0 = 0.f, a1 = 0.f;
#pragma unroll
    for (int i = 0; i < 16; i++) {
        int kx = b * 16 + i;
        float hp = hash_proj[kx];
        const float* wr = Wb + (size_t)(Dd + kx) * Dd;
        a0 = fmaf(hp, wr[t], a0);
        a1 = fmaf(hp, wr[t + 256], a1);
    }
    part[b * Dd + t]       = a0;
    part[b * Dd + t + 256] = a1;
}
__global__ __launch_bounds__(256)
void hvec_red_kernel(const float* __restrict__ part, float* __restrict__ hvec) {
    const int n = blockIdx.x * 256 + threadIdx.x;   // 2 blocks
    float acc = 0.f;
#pragma unroll
    for (int b = 0; b < 32; b++) acc += part[b * Dd + n];
    hvec[n] = acc;
}

// ---------------- f32 -> f16 convert (emb) ----------------------------------
__global__ void conv_kernel(const float* __restrict__ src, f16* __restrict__ dst, int n) {
    int i = blockIdx.x * 256 + threadIdx.x;
    if (i < n) dst[i] = (f16)src[i];
}

// ---------------- bias concat for fused QKV ---------------------------------
__global__ void pack_bias_kernel(const float* __restrict__ bq, const float* __restrict__ bk,
                                 const float* __restrict__ bv, float* __restrict__ bqkv) {
    int t = blockIdx.x * 256 + threadIdx.x;   // L*1536 = 6144
    int l = t / 1536, r = t % 1536;
    const float* src = (r < 512) ? bq : ((r < 1024) ? bk : bv);
    bqkv[t] = src[l * 512 + (r & 511)];
}

// ---------------- convert + transpose: W (K x N f32) -> Wt (N x K f16) ------
__global__ __launch_bounds__(256)
void trans_kernel(const float* __restrict__ src, f16* __restrict__ dst,
                  int K, int N, long sStride, long dStride) {
    __shared__ float tile[32][33];
    const float* s = src + blockIdx.z * sStride;
    f16* d = dst + blockIdx.z * dStride;
    int k0 = blockIdx.y * 32, n0 = blockIdx.x * 32;
    int tx = threadIdx.x & 31, ty = threadIdx.x >> 5;   // ty 0..7
#pragma unroll
    for (int i = 0; i < 32; i += 8)
        tile[ty + i][tx] = s[(long)(k0 + ty + i) * N + n0 + tx];
    __syncthreads();
#pragma unroll
    for (int i = 0; i < 32; i += 8)
        d[(long)(n0 + ty + i) * K + k0 + tx] = (f16)tile[tx][ty + i];
}

// ---- merged transpose for the four 512x512 weight families (z = w*4 + l) ---
__global__ __launch_bounds__(256)
void trans4_kernel(const float* __restrict__ Wq, const float* __restrict__ Wk,
                   const float* __restrict__ Wv, const float* __restrict__ Wo,
                   f16* __restrict__ Wqkvt, f16* __restrict__ Wot) {
    __shared__ float tile[32][33];
    const int which = blockIdx.z >> 2, l = blockIdx.z & 3;
    const float* s;
    f16* d;
    switch (which) {
        case 0: s = Wq + (size_t)l * 262144; d = Wqkvt + (size_t)l * 786432;          break;
        case 1: s = Wk + (size_t)l * 262144; d = Wqkvt + (size_t)l * 786432 + 262144; break;
        case 2: s = Wv + (size_t)l * 262144; d = Wqkvt + (size_t)l * 786432 + 524288; break;
        default:s = Wo + (size_t)l * 262144; d = Wot   + (size_t)l * 262144;          break;
    }
    int k0 = blockIdx.y * 32, n0 = blockIdx.x * 32;
    int tx = threadIdx.x & 31, ty = threadIdx.x >> 5;
#pragma unroll
    for (int i = 0; i < 32; i += 8)
        tile[ty + i][tx] = s[(long)(k0 + ty + i) * 512 + n0 + tx];
    __syncthreads();
#pragma unroll
    for (int i = 0; i < 32; i += 8)
        d[(long)(n0 + ty + i) * 512 + k0 + tx] = (f16)tile[tx][ty + i];
}

// ---------------- MFMA f16 GEMM: C = op(A @ Wt^T + bias), BK=64, TM=64 ------
// Register staging, 2 barriers/iter (R11 post-mortem: explicit dbuf regresses).
// TM=64 doubles blocks/CU vs TM=128 (latency-bound fleet, grid was 1-2/CU).
// Waves: TN=64 -> 2x2 (wave=32x32); TN=128 -> 1x4 (wave=64x32).
// LDS: 16B chunks, row = 8 chunks; chunk (m,kb) at slot m*8 + (kb^(m&7)).
template<int TN, bool GATHER, bool RANK1, bool GELU, bool RES, bool OUT16>
__global__ __launch_bounds__(256)
void mgemm(const f16* __restrict__ A, const f16* __restrict__ Wt,
           const float* __restrict__ bias,
           const int* __restrict__ gidx,
           const int* __restrict__ hashes, const float* __restrict__ hvec,
           const float* __restrict__ resid,
           void* __restrict__ Cout, int M, int N, int K) {
    constexpr int TM  = 64;
    constexpr int WRN = (TN == 64) ? 2 : 1;   // wave-grid rows
    constexpr int WCN = 4 / WRN;              // wave-grid cols
    constexpr int WRE = TM / WRN;             // wave row extent (32 or 64)
    constexpr int NIT = WRE / 16;             // row tiles/wave (2 or 4)
    constexpr int ACH = TM * 8;               // A chunks (16B), BK=64 f16 = 8/row
    constexpr int BCH = TN * 8;
    constexpr int NCH = ACH + BCH;
    constexpr int NCHT = NCH / 256;           // 4 or 6
    __shared__ __align__(16) f16 sm[NCH * 8];
    const int t = threadIdx.x;
    const int lane = t & 63;
    const int w = t >> 6;
    const int wr = w / WCN, wc = w % WCN;
    const int i0 = blockIdx.y * TM, j0 = blockIdx.x * TN;

    const f16* gsrc[NCHT];
#pragma unroll
    for (int q = 0; q < NCHT; q++) {
        int c = t + q * 256;
        if (c < ACH) {
            int m = c >> 3, kb = (c & 7) ^ (m & 7);
            long row = GATHER ? (long)gidx[i0 + m] : (long)(i0 + m);
            gsrc[q] = A + row * K + kb * 8;
        } else {
            int cc = c - ACH;
            int n = cc >> 3, kb = (cc & 7) ^ (n & 7);
            gsrc[q] = Wt + (long)(j0 + n) * K + kb * 8;
        }
    }

    f32x4 acc[NIT][2];
#pragma unroll
    for (int i = 0; i < NIT; i++)
#pragma unroll
        for (int j = 0; j < 2; j++) acc[i][j] = (f32x4){0.f, 0.f, 0.f, 0.f};

    for (int kt = 0; kt < K; kt += 64) {
        f16x8 stg[NCHT];
#pragma unroll
        for (int q = 0; q < NCHT; q++) stg[q] = *(const f16x8*)(gsrc[q] + kt);
        __syncthreads();   // previous iteration's LDS reads complete
#pragma unroll
        for (int q = 0; q < NCHT; q++)
            *(f16x8*)(sm + (t + q * 256) * 8) = stg[q];
        __syncthreads();

#pragma unroll
        for (int kh = 0; kh < 2; kh++) {
            f16x8 af[NIT], bf[2];
#pragma unroll
            for (int i = 0; i < NIT; i++) {
                int m = wr * WRE + i * 16 + (lane & 15);
                int sl = m * 8 + ((kh * 4 + (lane >> 4)) ^ (m & 7));
                af[i] = *(const f16x8*)(sm + sl * 8);
            }
#pragma unroll
            for (int j = 0; j < 2; j++) {
                int n = wc * 32 + j * 16 + (lane & 15);
                int sl = ACH + n * 8 + ((kh * 4 + (lane >> 4)) ^ (n & 7));
                bf[j] = *(const f16x8*)(sm + sl * 8);
            }
#pragma unroll
            for (int i = 0; i < NIT; i++)
#pragma unroll
                for (int j = 0; j < 2; j++)
                    acc[i][j] = __builtin_amdgcn_mfma_f32_16x16x32_f16(af[i], bf[j], acc[i][j], 0, 0, 0);
        }
    }

    // epilogue: C/D layout col=lane&15, row=(lane>>4)*4+v
    float* Cf = (float*)Cout;
    f16*   Ch = (f16*)Cout;
#pragma unroll
    for (int i = 0; i < NIT; i++) {
        int rbase = i0 + wr * WRE + i * 16 + ((lane >> 4) << 2);
#pragma unroll
        for (int v = 0; v < 4; v++) {
            int row = rbase + v;
            float hterm = RANK1 ? (float)hashes[row] * INV_MOD : 0.f;
#pragma unroll
            for (int j = 0; j < 2; j++) {
                int col = j0 + wc * 32 + j * 16 + (lane & 15);
                float val = acc[i][j][v] + bias[col];
                if (RANK1) val += hterm * hvec[col];
                if (GELU)  val = 0.5f * val * (1.f + erff(val * 0.7071067811865475f));
                if (RES)   val += resid[(long)row * N + col];
                if (OUT16) Ch[(long)row * N + col] = (f16)val;
                else       Cf[(long)row * N + col] = val;
            }
        }
    }
}

// ---------------- MFMA Poincare "arg" matrix (BK=64, TM=TN=64) --------------
// poshl: 2048 x 1024 f16, row = [hi(512) | lo(512)], pos ~= hi+lo (22-bit).
// Writes arg = max(1 + 2c*d2/denom, 1) — MONOTONE in dist, so top-k on arg
// equals top-k on dist; acosh deferred to the 32 winners/row (topk_kernel).
__global__ __launch_bounds__(256)
void mdist_kernel(const f16* __restrict__ poshl, const float* __restrict__ xx,
                  const float* __restrict__ scal, float* __restrict__ dist) {
    constexpr int TM = 64, TN = 64;
    constexpr int ACH = TM * 8, BCH = TN * 8, NCH = ACH + BCH;   // 1024
    constexpr int NCHT = NCH / 256;                               // 4
    constexpr int KK = 1024;
    __shared__ __align__(16) f16 sm[NCH * 8];
    const int t = threadIdx.x;
    const int lane = t & 63;
    const int w = t >> 6;
    const int wr = w >> 1, wc = w & 1;
    const int i0 = blockIdx.y * TM, j0 = blockIdx.x * TN;

    const f16* gsrc[NCHT];
#pragma unroll
    for (int q = 0; q < NCHT; q++) {
        int c = t + q * 256;
        if (c < ACH) {
            int m = c >> 3, kb = (c & 7) ^ (m & 7);
            gsrc[q] = poshl + (long)(i0 + m) * KK + kb * 8;
        } else {
            int cc = c - ACH;
            int n = cc >> 3, kb = (cc & 7) ^ (n & 7);
            gsrc[q] = poshl + (long)(j0 + n) * KK + kb * 8;
        }
    }

    f32x4 acc[2][2];
#pragma unroll
    for (int i = 0; i < 2; i++)
#pragma unroll
        for (int j = 0; j < 2; j++) acc[i][j] = (f32x4){0.f, 0.f, 0.f, 0.f};

    for (int kt = 0; kt < KK; kt += 64) {
        f16x8 stg[NCHT];
#pragma unroll
        for (int q = 0; q < NCHT; q++) stg[q] = *(const f16x8*)(gsrc[q] + kt);
        __syncthreads();
#pragma unroll
        for (int q = 0; q < NCHT; q++)
            *(f16x8*)(sm + (t + q * 256) * 8) = stg[q];
        __syncthreads();

#pragma unroll
        for (int kh = 0; kh < 2; kh++) {
            f16x8 af[2], bf[2];
#pragma unroll
            for (int i = 0; i < 2; i++) {
                int m = wr * 32 + i * 16 + (lane & 15);
                int sl = m * 8 + ((kh * 4 + (lane >> 4)) ^ (m & 7));
                af[i] = *(const f16x8*)(sm + sl * 8);
            }
#pragma unroll
            for (int j = 0; j < 2; j++) {
                int n = wc * 32 + j * 16 + (lane & 15);
                int sl = ACH + n * 8 + ((kh * 4 + (lane >> 4)) ^ (n & 7));
                bf[j] = *(const f16x8*)(sm + sl * 8);
            }
#pragma unroll
            for (int i = 0; i < 2; i++)
#pragma unroll
                for (int j = 0; j < 2; j++)
                    acc[i][j] = __builtin_amdgcn_mfma_f32_16x16x32_f16(af[i], bf[j], acc[i][j], 0, 0, 0);
        }
    }

    const float c = scal[0];
#pragma unroll
    for (int i = 0; i < 2; i++) {
        int rbase = i0 + wr * 32 + i * 16 + ((lane >> 4) << 2);
#pragma unroll
        for (int v = 0; v < 4; v++) {
            int row = rbase + v;
            float xi = xx[row];
#pragma unroll
            for (int j = 0; j < 2; j++) {
                int col = j0 + wc * 32 + j * 16 + (lane & 15);
                float xj = xx[col];
                float d2 = fmaxf(xi + xj - 2.f * acc[i][j][v], 0.f);
                float denom = (1.f - c * xi) * (1.f - c * xj) + 1e-8f;
                float arg = fmaxf(1.f + 2.f * c * d2 / denom, 1.f);
                dist[(long)row * Nn + col] = arg;
            }
        }
    }
}

// ---------------- LayerNorm (512), single wave, float4, shuffle-only --------
__global__ __launch_bounds__(64)
void ln_kernel(const float* __restrict__ x, const float* __restrict__ g,
               const float* __restrict__ be, f16* __restrict__ xn) {
    const int row = blockIdx.x, t = threadIdx.x;
    const float4* xr = (const float4*)(x + (size_t)row * Dd);
    float4 v0 = xr[t], v1 = xr[t + 64];
    float s = v0.x + v0.y + v0.z + v0.w + v1.x + v1.y + v1.z + v1.w;
#pragma unroll
    for (int off = 32; off; off >>= 1) s += __shfl_xor(s, off, 64);
    float mean = s * (1.f / Dd);
    float d0x = v0.x - mean, d0y = v0.y - mean, d0z = v0.z - mean, d0w = v0.w - mean;
    float d1x = v1.x - mean, d1y = v1.y - mean, d1z = v1.z - mean, d1w = v1.w - mean;
    float q = d0x*d0x + d0y*d0y + d0z*d0z + d0w*d0w
            + d1x*d1x + d1y*d1y + d1z*d1z + d1w*d1w;
#pragma unroll
    for (int off = 32; off; off >>= 1) q += __shfl_xor(q, off, 64);
    float rstd = rsqrtf(q * (1.f / Dd) + 1e-5f);
    float4 g0 = ((const float4*)g)[t], g1v = ((const float4*)g)[t + 64];
    float4 b0 = ((const float4*)be)[t], b1v = ((const float4*)be)[t + 64];
    f16* xo = xn + (size_t)row * Dd;
    f16x4 o0, o1;
    o0[0] = (f16)(d0x * rstd * g0.x + b0.x);
    o0[1] = (f16)(d0y * rstd * g0.y + b0.y);
    o0[2] = (f16)(d0z * rstd * g0.z + b0.z);
    o0[3] = (f16)(d0w * rstd * g0.w + b0.w);
    o1[0] = (f16)(d1x * rstd * g1v.x + b1v.x);
    o1[1] = (f16)(d1y * rstd * g1v.y + b1v.y);
    o1[2] = (f16)(d1z * rstd * g1v.z + b1v.z);
    o1[3] = (f16)(d1w * rstd * g1v.w + b1v.w);
    *(f16x4*)(xo + t * 4)         = o0;
    *(f16x4*)(xo + (t + 64) * 4)  = o1;
}

// ---------------- expmap0 -> poshl (f16 hi|lo), xx = |pos|^2 (f32) ----------
__global__ __launch_bounds__(256)
void expmap_kernel(const float* __restrict__ vt, const float* __restrict__ scal,
                   f16* __restrict__ poshl, float* __restrict__ xx) {
    __shared__ float red[256];
    const int row = blockIdx.x, t = threadIdx.x;
    const float* vr = vt + (size_t)row * Dd;
    float v0 = vr[t], v1 = vr[t + 256];
    red[t] = v0 * v0 + v1 * v1;
    __syncthreads();
    for (int off = 128; off; off >>= 1) {
        if (t < off) red[t] += red[t + off];
        __syncthreads();
    }
    float total = red[0];
    float vn = fmaxf(sqrtf(total), 1e-8f);
    float sc = scal[1];
    float factor = tanhf(sc * vn) / (sc * vn);
    float p0 = factor * v0, p1 = factor * v1;
    f16 h0 = (f16)p0, h1 = (f16)p1;
    f16* pr = poshl + (size_t)row * 1024;
    pr[t]             = h0;
    pr[t + 256]       = h1;
    pr[512 + t]       = (f16)(p0 - (float)h0);
    pr[512 + t + 256] = (f16)(p1 - (float)h1);
    if (t == 0) xx[row] = factor * factor * total;
}

// ---------------- top-K=32 on args: one wave per row, f32 in registers ------
// Selects smallest args (monotone = smallest dists); winner converts to
// dist = acosh(arg)/sqrt(c) on write (32 conversions per row).
__global__ __launch_bounds__(64)
void topk_kernel(const float* __restrict__ dist, const float* __restrict__ scal,
                 float* __restrict__ outd, int* __restrict__ outi) {
    const int lane = threadIdx.x;
    const int n = blockIdx.x;
    const float sqc = scal[1];
    const float* dr = dist + (size_t)n * Nn;
    float val[32];
#pragma unroll
    for (int i = 0; i < 32; i++) val[i] = dr[i * 64 + lane];
    float lmin = val[0];
    int   li   = 0;
#pragma unroll
    for (int i = 1; i < 32; i++) {
        if (val[i] < lmin) { lmin = val[i]; li = i; }
    }

    for (int s = 0; s < Kk; s++) {
        float wmin = lmin;
#pragma unroll
        for (int off = 32; off; off >>= 1)
            wmin = fminf(wmin, __shfl_xor(wmin, off, 64));
        const bool tiedl = (lmin == wmin);
        unsigned long long tied = __ballot(tiedl);
        const int gidx = li * 64 + lane;
        bool owner;
        if (__popcll(tied) == 1) {          // wave-uniform branch (common case)
            owner = tiedl;
        } else {                             // exact ties: lowest global index
            int cand = tiedl ? gidx : 0x7FFFFFFF;
#pragma unroll
            for (int off = 32; off; off >>= 1)
                cand = min(cand, __shfl_xor(cand, off, 64));
            owner = tiedl && (gidx == cand);
        }
        if (owner) {
            outd[n * Kk + s] = acoshf(wmin) / sqc;
            outi[n * Kk + s] = gidx;
#pragma unroll
            for (int i = 0; i < 32; i++)
                if (i == li) val[i] = 3.0e38f;
            lmin = val[0]; li = 0;
#pragma unroll
            for (int i = 1; i < 32; i++) {
                if (val[i] < lmin) { lmin = val[i]; li = i; }
            }
        }
    }
}

// ---------------- sparse attention: one block per (b,n), all 8 heads --------
#define KVSTR 520   // row stride in f16 (512 + 8 pad -> bank-offset rows)
__global__ __launch_bounds__(256)
void attn_kernel(const f16* __restrict__ qkv, const float* __restrict__ adist,
                 const int* __restrict__ aidx, const float* __restrict__ scal,
                 int layer, f16* __restrict__ ao) {
    __shared__ __align__(16) f16 kv[64 * KVSTR];   // [0..31]=K rows, [32..63]=V rows
    __shared__ __align__(16) f16 qs[512];
    __shared__ float ps[Hh][Kk];
    __shared__ float sdist[Kk];
    __shared__ int   sidx[Kk];
    const int t = threadIdx.x;
    const int b = blockIdx.x >> 11, n = blockIdx.x & (Nn - 1);
    const float inv_tau = scal[2 + layer];

    if (t < Kk) {
        sidx[t]  = aidx[n * Kk + t];
        sdist[t] = adist[n * Kk + t];
    }
    __syncthreads();

    {
        const size_t qrow = (size_t)(b * Nn + n) * 1536;
#pragma unroll
        for (int q = 0; q < 16; q++) {
            int c = q * 256 + t;
            int j = c >> 7, ci = c & 127;        // ci<64: K, else V
            size_t src = (size_t)(b * Nn + sidx[j]) * 1536 + 512 + ci * 8;
            int dst = (ci < 64) ? (j * KVSTR + ci * 8)
                                : ((32 + j) * KVSTR + (ci - 64) * 8);
            *(f16x8*)(kv + dst) = *(const f16x8*)(qkv + src);
        }
        if (t < 64) *(f16x8*)(qs + t * 8) = *(const f16x8*)(qkv + qrow + t * 8);
    }
    __syncthreads();

    const int h = t >> 5, j = t & 31;
    float dot = 0.f;
#pragma unroll
    for (int i = 0; i < 8; i++) {
        f16x8 qa = *(const f16x8*)(qs + h * HDh + i * 8);
        f16x8 ka = *(const f16x8*)(kv + j * KVSTR + h * HDh + i * 8);
#pragma unroll
        for (int m = 0; m < 4; m++) {
            f16x2 qp = {qa[2 * m], qa[2 * m + 1]};
            f16x2 kp = {ka[2 * m], ka[2 * m + 1]};
            dot = __builtin_amdgcn_fdot2(qp, kp, dot, false);
        }
    }
    float s = dot * SCALE_QK - sdist[j] * inv_tau;
    float mx = s;
#pragma unroll
    for (int off = 16; off; off >>= 1) mx = fmaxf(mx, __shfl_xor(mx, off, 64));
    float e = expf(s - mx);
    float sum = e;
#pragma unroll
    for (int off = 16; off; off >>= 1) sum += __shfl_xor(sum, off, 64);
    ps[h][j] = e / sum;
    __syncthreads();

    const int d2 = t & 31;
    float a0 = 0.f, a1 = 0.f;
#pragma unroll
    for (int jj = 0; jj < Kk; jj++) {
        float p = ps[h][jj];
        f16x2 vv = *(const f16x2*)(kv + (32 + jj) * KVSTR + h * HDh + d2 * 2);
        a0 = fmaf(p, (float)vv[0], a0);
        a1 = fmaf(p, (float)vv[1], a1);
    }
    f16x2 outv; outv[0] = (f16)a0; outv[1] = (f16)a1;
    *(f16x2*)(ao + (size_t)(b * Nn + n) * Dd + h * HDh + d2 * 2) = outv;
}

// ---------------- final projection: out = x[:, -1, :] @ Wout + bout ---------
__global__ void out_kernel(const float* __restrict__ x, const float* __restrict__ Wout,
                           const float* __restrict__ bout, float* __restrict__ out) {
    const int b = blockIdx.x, vc = threadIdx.x;   // 2 blocks x 256 threads
    const float* xr = x + ((size_t)(b * Nn + (Nn - 1))) * Dd;
    float acc = bout[vc];
    for (int d = 0; d < Dd; d++) acc = fmaf(xr[d], Wout[(size_t)d * Vv + vc], acc);
    out[b * Vv + vc] = acc;
}

// ---------------- workspace layout (bytes) — fully disjoint -----------------
static constexpr size_t X_OFF     = 0;          // 8388608  f32 x
static constexpr size_t XN16_OFF  = 8388608;    // 4194304  f16 xn
static constexpr size_t QKV16_OFF = 12582912;   // 12582912 f16 qkv
static constexpr size_t AO16_OFF  = 25165824;   // 4194304  f16 ao | f16 poshl (pre)
static constexpr size_t H1_OFF    = 29360128;   // 16777216 f16 h1 | f32 arg-matrix (pre)
static constexpr size_t AD_OFF    = 46137344;   // 262144
static constexpr size_t AI_OFF    = 46399488;   // 262144
static constexpr size_t SC_OFF    = 46661632;   // 256
static constexpr size_t HV_OFF    = 46661888;   // 2048
static constexpr size_t XX_OFF    = 46663936;   // 8192
static constexpr size_t BQKV_OFF  = 46672128;   // 32768
static constexpr size_t EMB16_OFF = 46704896;   // 262144
static constexpr size_t WBT_OFF   = 46967040;   // 524288
static constexpr size_t WQKVT_OFF = 47491328;   // 6291456  [L][1536][512]
static constexpr size_t WOT_OFF   = 53782784;   // 2097152  [L][512][512]
static constexpr size_t W1T_OFF   = 55879936;   // 8388608  [L][2048][512]
static constexpr size_t W2T_OFF   = 64268544;   // 8388608  [L][512][2048]
static constexpr size_t HP_OFF    = 72657152;   // 65536    hvec partials

extern "C" void kernel_launch(void* const* d_in, const int* in_sizes, int n_in,
                              void* d_out, int out_size, void* d_ws, size_t ws_size,
                              hipStream_t stream) {
    (void)in_sizes; (void)n_in; (void)out_size; (void)ws_size;
    const int*   hashes    = (const int*)  d_in[0];
    const int*   indices   = (const int*)  d_in[1];
    const float* emb       = (const float*)d_in[2];
    const float* hash_proj = (const float*)d_in[3];
    const float* Wb        = (const float*)d_in[4];
    const float* bb        = (const float*)d_in[5];
    const float* log_c     = (const float*)d_in[6];
    const float* pos_t     = (const float*)d_in[7];
    const float* Wq        = (const float*)d_in[8];
    const float* bq        = (const float*)d_in[9];
    const float* Wk        = (const float*)d_in[10];
    const float* bk        = (const float*)d_in[11];
    const float* Wv        = (const float*)d_in[12];
    const float* bv        = (const float*)d_in[13];
    const float* Wo        = (const float*)d_in[14];
    const float* bo        = (const float*)d_in[15];
    const float* W1        = (const float*)d_in[16];
    const float* b1        = (const float*)d_in[17];
    const float* W2        = (const float*)d_in[18];
    const float* b2        = (const float*)d_in[19];
    const float* g1        = (const float*)d_in[20];
    const float* be1       = (const float*)d_in[21];
    const float* g2        = (const float*)d_in[22];
    const float* be2       = (const float*)d_in[23];
    const float* log_tau   = (const float*)d_in[24];
    const float* Wout      = (const float*)d_in[25];
    const float* bout      = (const float*)d_in[26];

    char* ws = (char*)d_ws;
    float* x      = (float*)(ws + X_OFF);
    f16*   xn16   = (f16*)  (ws + XN16_OFF);
    f16*   qkv16  = (f16*)  (ws + QKV16_OFF);
    f16*   ao16   = (f16*)  (ws + AO16_OFF);
    f16*   h1     = (f16*)  (ws + H1_OFF);
    float* adist  = (float*)(ws + AD_OFF);
    int*   aidx   = (int*)  (ws + AI_OFF);
    float* scal   = (float*)(ws + SC_OFF);
    float* hvec   = (float*)(ws + HV_OFF);
    float* xxb    = (float*)(ws + XX_OFF);
    float* bqkv   = (float*)(ws + BQKV_OFF);
    f16*   emb16  = (f16*)  (ws + EMB16_OFF);
    f16*   Wbt    = (f16*)  (ws + WBT_OFF);
    f16*   Wqkvt  = (f16*)  (ws + WQKVT_OFF);
    f16*   Wot    = (f16*)  (ws + WOT_OFF);
    f16*   W1t    = (f16*)  (ws + W1T_OFF);
    f16*   W2t    = (f16*)  (ws + W2T_OFF);
    float* hpart  = (float*)(ws + HP_OFF);
    f16*   poshl  = (f16*)  (ws + AO16_OFF);   // alias, pre-loop only
    float* distb  = (float*)(ws + H1_OFF);     // alias, pre-loop only

    // --- weight prep (runs every call; graph-capture safe) ---
    scal_kernel<<<1, 64, 0, stream>>>(log_c, log_tau, scal);
    hvec_part_kernel<<<32, 256, 0, stream>>>(hash_proj, Wb, hpart);
    hvec_red_kernel<<<2, 256, 0, stream>>>(hpart, hvec);
    pack_bias_kernel<<<24, 256, 0, stream>>>(bq, bk, bv, bqkv);
    conv_kernel<<<(Vv * Dd + 255) / 256, 256, 0, stream>>>(emb, emb16, Vv * Dd);
    trans_kernel<<<dim3(16, 16, 1), 256, 0, stream>>>(Wb, Wbt, 512, 512, 0, 0);
    trans4_kernel<<<dim3(16, 16, 16), 256, 0, stream>>>(Wq, Wk, Wv, Wo, Wqkvt, Wot);
    trans_kernel<<<dim3(64, 16, Ll), 256, 0, stream>>>(W1, W1t, 512, 2048, 1048576, 1048576);
    trans_kernel<<<dim3(16, 64, Ll), 256, 0, stream>>>(W2, W2t, 2048, 512, 1048576, 1048576);

    // --- input projection: x = emb16[indices] @ Wbt^T + hash*hvec + bb (f32 out)
    mgemm<64, true, true, false, false, false><<<dim3(8, 64), 256, 0, stream>>>(
        emb16, Wbt, bb, indices, hashes, hvec, nullptr, x, Mrows, Dd, Dd);

    // --- kNN preprocessing: expmap (hi/lo split) -> MFMA arg -> topk+acosh ---
    expmap_kernel<<<Nn, 256, 0, stream>>>(pos_t, scal, poshl, xxb);
    mdist_kernel<<<dim3(32, 32), 256, 0, stream>>>(poshl, xxb, scal, distb);
    topk_kernel<<<Nn, 64, 0, stream>>>(distb, scal, adist, aidx);

    for (int l = 0; l < Ll; l++) {
        ln_kernel<<<Mrows, 64, 0, stream>>>(x, g1 + l * Dd, be1 + l * Dd, xn16);
        // fused QKV: M x 1536, f16 out
        mgemm<128, false, false, false, false, true><<<dim3(12, 64), 256, 0, stream>>>(
            xn16, Wqkvt + (size_t)l * 786432, bqkv + l * 1536,
            nullptr, nullptr, nullptr, nullptr, qkv16, Mrows, 1536, Dd);
        attn_kernel<<<Bb * Nn, 256, 0, stream>>>(qkv16, adist, aidx, scal, l, ao16);
        // Wo + residual, f32 out
        mgemm<64, false, false, false, true, false><<<dim3(8, 64), 256, 0, stream>>>(
            ao16, Wot + (size_t)l * 262144, bo + l * Dd,
            nullptr, nullptr, nullptr, x, x, Mrows, Dd, Dd);
        ln_kernel<<<Mrows, 64, 0, stream>>>(x, g2 + l * Dd, be2 + l * Dd, xn16);
        // W1 + GELU, f16 out
        mgemm<128, false, false, true, false, true><<<dim3(16, 64), 256, 0, stream>>>(
            xn16, W1t + (size_t)l * 1048576, b1 + l * 4 * Dd,
            nullptr, nullptr, nullptr, nullptr, h1, Mrows, 4 * Dd, Dd);
        // W2 + residual, f32 out
        mgemm<64, false, false, false, true, false><<<dim3(8, 64), 256, 0, stream>>>(
            h1, W2t + (size_t)l * 1048576, b2 + l * Dd,
            nullptr, nullptr, nullptr, x, x, Mrows, Dd, 4 * Dd);
    }

    out_kernel<<<Bb, Vv, 0, stream>>>(x, Wout, bout, (float*)d_out);
}